// Round 10
// baseline (743.701 us; speedup 1.0000x reference)
//
#include <hip/hip_runtime.h>
#include <hip/hip_bf16.h>

#define NN 100000
#define DD 64
#define EE 400000
#define TT 5

#define CH 160                   /* node buckets (no t in key) */
#define BPC 625                  /* NN/CH exact */
#define PSPLIT 32                /* edge slices per t */
#define PESL (EE / PSPLIT)       /* 12,500 edges per slice */
#define NSB (PSPLIT * TT)        /* 160 slice-blocks */
#define PBN (CH * NSB)           /* 25,600 partition counters = 1024*25 */
#define NBIN (BPC * TT)          /* 3,125 bins per bucket (src_local*5+t) */
#define NETOT (TT * EE)          /* 2,000,000 */

typedef __bf16 bf16x8 __attribute__((ext_vector_type(8)));
typedef float  f32x4  __attribute__((ext_vector_type(4)));

// ws layout (bytes) — total 40,914,240 envelope
#define OFF_XBF  0u            // N*D ushort      = 12,800,000
#define OFF_WT   12800000u     // T*64*128 ushort = 81,920
#define OFF_CTOT 12881920u     // T*N u32 (cnt_tot) = 2,000,000
#define OFF_WGT  14881920u     // T f32 (pad 128)
#define OFF_PB   14882048u     // 25,600 u32 partition counts (102,400 B; fits
                               //   the freed former-cur region, ends 14,984,448)
#define OFF_PE   16886080u     // 2M u32 packed (srcl:10|t:3|dst:17) = 8,000,000
#define OFF_DST  24914240u     // 2M int (sorted dst) = 8,000,000
#define OFF_SEG  32914240u     // 2M int (packed node<<3|t) = 8,000,000 -> 40,914,240

__device__ __forceinline__ unsigned short f2bf(float f) {
    union { float f; unsigned u; } v; v.f = f;
    unsigned u = v.u;
    return (unsigned short)((u + 0x7FFFu + ((u >> 16) & 1u)) >> 16);  // RNE
}

// ---------------- Phase 1: init / convert / out-zero, FUSED pcount (160
// node-buckets, t-free key) ---------------------------------------------------
__global__ __launch_bounds__(256) void k_init(
        const float* __restrict__ x, const float* __restrict__ W,
        const float* __restrict__ ea, const int* __restrict__ edges,
        unsigned short* __restrict__ xbf, unsigned short* __restrict__ wT,
        float* __restrict__ wgt, float* __restrict__ out,
        unsigned* __restrict__ pcnt) {
    int i = blockIdx.x * blockDim.x + threadIdx.x;   // grid covers N*D exactly
    if (i < NN * DD) {
        out[i] = 0.0f;
        xbf[i] = f2bf(x[i]);
    }
    if (i < TT * 128 * 64) {
        int t = i >> 13;          // /8192
        int rem = i & 8191;
        int d = rem >> 7;         // /128
        int k = rem & 127;
        wT[i] = f2bf(W[t * 8192 + k * 64 + d]);   // wT[t][d][k] = W[t][k][d]
    }
    if (i == 0) {
        float m = -1e30f;
        for (int t = 0; t < TT; t++) m = fmaxf(m, ea[t]);
        float e[TT]; float s = 0.0f;
        for (int t = 0; t < TT; t++) { e[t] = __expf(ea[t] - m); s += e[t]; }
        for (int t = 0; t < TT; t++) wgt[t] = e[t] / s;
    }
    // fused pcount: 160 slice-blocks on blocks 0..159 (block-uniform branch)
    if (blockIdx.x < NSB) {
        const int sb = blockIdx.x;                  // = t*32 + s
        const int s = sb & (PSPLIT - 1);
        const int t = sb >> 5;
        __shared__ unsigned h[CH];
        if (threadIdx.x < CH) h[threadIdx.x] = 0u;
        __syncthreads();
        const int4* srcp = reinterpret_cast<const int4*>(edges + (size_t)t * 2 * EE + s * PESL);
        for (int j = threadIdx.x; j < PESL / 4; j += 256) {
            int4 v = srcp[j];
            atomicAdd(&h[(unsigned)v.x / BPC], 1u);
            atomicAdd(&h[(unsigned)v.y / BPC], 1u);
            atomicAdd(&h[(unsigned)v.z / BPC], 1u);
            atomicAdd(&h[(unsigned)v.w / BPC], 1u);
        }
        __syncthreads();
        if (threadIdx.x < CH) pcnt[threadIdx.x * NSB + sb] = h[threadIdx.x];
    }
}

// ---------------- Phase 2: exclusive scan of 25,600 partition counters
// (1 block, 1024 thr x 25; pb too big now for redundant per-block scans) -----
__global__ void k_pscan(unsigned* __restrict__ pb) {
    __shared__ unsigned s[1024];
    const int tid = threadIdx.x;
    unsigned v[25]; unsigned sum = 0u;
#pragma unroll
    for (int j = 0; j < 25; j++) { v[j] = pb[tid * 25 + j]; sum += v[j]; }
    s[tid] = sum;
    __syncthreads();
    unsigned inc = sum;
    for (int d = 1; d < 1024; d <<= 1) {
        unsigned a = (tid >= d) ? s[tid - d] : 0u;
        __syncthreads();
        inc += a;
        s[tid] = inc;
        __syncthreads();
    }
    unsigned run = inc - sum;
#pragma unroll
    for (int j = 0; j < 25; j++) { unsigned c = v[j]; pb[tid * 25 + j] = run; run += c; }
}

// ---------------- Phase 3: partition scatter into node-buckets.
// pe = (src_local:10 | t:3 | dst:17). ----------------------------------------
__global__ __launch_bounds__(256) void k_pscat(const int* __restrict__ edges,
                                               const unsigned* __restrict__ pbase,
                                               unsigned* __restrict__ pe) {
    const int s = blockIdx.x, t = blockIdx.y;
    const int sb = t * PSPLIT + s;
    __shared__ unsigned lofs[CH];
    if (threadIdx.x < CH) lofs[threadIdx.x] = pbase[threadIdx.x * NSB + sb];
    __syncthreads();
    const int* srcp = edges + (size_t)t * 2 * EE + s * PESL;
    const int* dstp = srcp + EE;
    const unsigned tb = (unsigned)t << 17;
    for (int i = threadIdx.x; i < PESL / 4; i += 256) {
        int4 v = reinterpret_cast<const int4*>(srcp)[i];
        int4 w = reinterpret_cast<const int4*>(dstp)[i];
        {
            unsigned c = (unsigned)v.x / BPC;
            unsigned o = atomicAdd(&lofs[c], 1u);
            pe[o] = (((unsigned)v.x - c * BPC) << 20) | tb | (unsigned)w.x;
        }
        {
            unsigned c = (unsigned)v.y / BPC;
            unsigned o = atomicAdd(&lofs[c], 1u);
            pe[o] = (((unsigned)v.y - c * BPC) << 20) | tb | (unsigned)w.y;
        }
        {
            unsigned c = (unsigned)v.z / BPC;
            unsigned o = atomicAdd(&lofs[c], 1u);
            pe[o] = (((unsigned)v.z - c * BPC) << 20) | tb | (unsigned)w.z;
        }
        {
            unsigned c = (unsigned)v.w / BPC;
            unsigned o = atomicAdd(&lofs[c], 1u);
            pe[o] = (((unsigned)v.w - c * BPC) << 20) | tb | (unsigned)w.w;
        }
    }
}

// ---------------- Phase 4: fused bucket sort, NODE-MAJOR bins (srcl*5+t).
// Produces sorted order keyed (node, t): all ~20 edges of a node contiguous.
// Writes cnt_tot + seg (packed node<<3|t) + sdst in one kernel. ---------------
__global__ __launch_bounds__(512) void k_bsort(const unsigned* __restrict__ pe,
                                               const unsigned* __restrict__ pb,
                                               unsigned* __restrict__ cnt_tot,
                                               int* __restrict__ sdst,
                                               int* __restrict__ seg) {
    const int c = blockIdx.x;
    const int tid = threadIdx.x;
    __shared__ unsigned h[NBIN];       // 12.5 KB
    __shared__ unsigned curl[NBIN];    // 12.5 KB
    __shared__ unsigned ssum[512];

    const unsigned st = pb[c * NSB];
    const unsigned en = (c == CH - 1) ? (unsigned)NETOT : pb[(c + 1) * NSB];

    for (int i = tid; i < NBIN; i += 512) h[i] = 0u;
    __syncthreads();

    // count (node-major bins)
    for (unsigned i = st + tid; i < en; i += 512) {
        unsigned p = pe[i];
        atomicAdd(&h[(p >> 20) * TT + ((p >> 17) & 7u)], 1u);
    }
    __syncthreads();

    // cnt_tot[t][n] for k_edge's scale
    for (int g = tid; g < NBIN; g += 512) {
        int sl = g / TT, t = g - sl * TT;
        cnt_tot[t * NN + c * BPC + sl] = h[g];
    }

    // block-wide exclusive scan of h -> absolute curl, fused seg-run fill
    {
        const int base = tid * 7;          // 512*7 = 3584 >= 3125
        unsigned v[7]; unsigned sum = 0u;
#pragma unroll
        for (int j = 0; j < 7; j++) {
            int g = base + j;
            v[j] = (g < NBIN) ? h[g] : 0u;
            sum += v[j];
        }
        ssum[tid] = sum;
        __syncthreads();
        unsigned inc = sum;
        for (int d = 1; d < 512; d <<= 1) {
            unsigned a = (tid >= d) ? ssum[tid - d] : 0u;
            __syncthreads();
            inc += a;
            ssum[tid] = inc;
            __syncthreads();
        }
        unsigned run = st + inc - sum;     // absolute exclusive prefix
#pragma unroll
        for (int j = 0; j < 7; j++) {
            int g = base + j;
            if (g < NBIN) {
                curl[g] = run;
                int sl = g / TT, t = g - sl * TT;
                int val = ((c * BPC + sl) << 3) | t;
                for (unsigned jj = 0; jj < v[j]; jj++) seg[run + jj] = val;
                run += v[j];
            }
        }
    }
    __syncthreads();

    // counting-sort scatter of dst
    for (unsigned i = st + tid; i < en; i += 512) {
        unsigned p = pe[i];
        unsigned bin = (p >> 20) * TT + ((p >> 17) & 7u);
        sdst[atomicAdd(&curl[bin], 1u)] = (int)(p & 0x1FFFFu);
    }
}

// ---------------- Phase 5 (v7): R0's k_edge structure on NODE-MAJOR order.
// Identical one-shot blocks / 128-edge tiles / gather / LDS shape / coalesced
// segmented flush (all proven). Two changes ONLY:
// (1) rows are mixed-t -> MFMA runs 5 passes (one per W[t]) with per-lane
//     cndmask zeroing A-fragments whose row-t != pass (each row contributes in
//     exactly one pass; acc shared). 32->160 MFMAs: affordable at 7% MfmaUtil.
// (2) flush key is NODE only: scale=wgt[t]/cnt[t][n] is per-row, so node-run
//     sums ARE out[n]. Bursts 553k -> ~162k (the validated WRITE model). -----
__global__ __launch_bounds__(256) void k_edge7(
    const unsigned short* __restrict__ xbf, const unsigned short* __restrict__ wT,
    const float* __restrict__ b, const int* __restrict__ sdst,
    const int* __restrict__ seg, const unsigned* __restrict__ cnt,
    const float* __restrict__ wgt, float* __restrict__ out) {
    const int e0 = blockIdx.x * 128;

    __shared__ __align__(16) unsigned short Ab[128][136];   // feats; reused as f32 proj[128][68]
    __shared__ float scale_s[128];
    __shared__ int   src_s[132];                             // padded
    __shared__ int   t_s[132];
    __shared__ float bs[TT * 64];                            // bias staged

    const int tid = threadIdx.x;

    // stage A: gather x rows; thread pair per sorted edge
    {
        int e = tid >> 1, half = tid & 1;
        int pos = e0 + e;
        int sv = seg[pos];
        int srcI = sv >> 3, tE = sv & 7;
        int idx = half ? sdst[pos] : srcI;
        const float4* g = reinterpret_cast<const float4*>(xbf + (size_t)idx * 64);
        float4* l = reinterpret_cast<float4*>(&Ab[e][half * 64]);
#pragma unroll
        for (int c = 0; c < 8; c++) l[c] = g[c];
        if (half == 0) {
            src_s[e] = srcI;
            t_s[e] = tE;
            scale_s[e] = wgt[tE] / (float)cnt[tE * NN + srcI];
        }
    }
    for (int i = tid; i < TT * 64; i += 256) bs[i] = b[i];
    __syncthreads();

    const int wv = tid >> 6, lane = tid & 63;
    const int m16 = lane & 15, quad = lane >> 4;

    const int tA0 = t_s[wv * 32 + m16];        // t of A-row, tm=0
    const int tA1 = t_s[wv * 32 + 16 + m16];   // t of A-row, tm=1

    bf16x8 z;
#pragma unroll
    for (int i = 0; i < 8; i++) z[i] = (__bf16)0.0f;

    f32x4 acc[2][4];
#pragma unroll
    for (int tm = 0; tm < 2; tm++)
#pragma unroll
        for (int tn = 0; tn < 4; tn++)
            acc[tm][tn] = (f32x4){0.f, 0.f, 0.f, 0.f};

#pragma unroll
    for (int p = 0; p < TT; p++) {
        const unsigned short* wrow = wT + (size_t)p * 8192;   // [d][k], 64x128
        const bool m0 = (tA0 == p), m1 = (tA1 == p);
#pragma unroll
        for (int kk = 0; kk < 128; kk += 32) {
            const int kb = kk + quad * 8;
            bf16x8 a0 = *reinterpret_cast<const bf16x8*>(&Ab[wv * 32 + m16][kb]);
            bf16x8 a1 = *reinterpret_cast<const bf16x8*>(&Ab[wv * 32 + 16 + m16][kb]);
            a0 = m0 ? a0 : z;
            a1 = m1 ? a1 : z;
            bf16x8 bfr[4];
#pragma unroll
            for (int tn = 0; tn < 4; tn++)
                bfr[tn] = *reinterpret_cast<const bf16x8*>(wrow + (tn * 16 + m16) * 128 + kb);
#pragma unroll
            for (int tn = 0; tn < 4; tn++) {
                acc[0][tn] = __builtin_amdgcn_mfma_f32_16x16x32_bf16(a0, bfr[tn], acc[0][tn], 0, 0, 0);
                acc[1][tn] = __builtin_amdgcn_mfma_f32_16x16x32_bf16(a1, bfr[tn], acc[1][tn], 0, 0, 0);
            }
        }
    }

    // all waves done reading Ab before overwrite with f32 proj
    __syncthreads();

    float* proj = reinterpret_cast<float*>(&Ab[0][0]);   // [128][68] f32
#pragma unroll
    for (int tm = 0; tm < 2; tm++) {
#pragma unroll
        for (int r = 0; r < 4; r++) {
            const int eloc = wv * 32 + tm * 16 + quad * 4 + r;
            const float s = scale_s[eloc];
            const int tE = t_s[eloc];
#pragma unroll
            for (int tn = 0; tn < 4; tn++) {
                float v = acc[tm][tn][r] + bs[tE * 64 + tn * 16 + m16];
                v = v > 0.f ? v : 0.f;
                proj[eloc * 68 + tn * 16 + m16] = v * s;
            }
        }
    }
    // NO barrier: wave wv wrote exactly proj rows [wv*32, wv*32+32) and reads
    // only those below.

    // wave-cooperative segmented reduce: flush on NODE change only
    {
        const int j0 = wv * 32;
        float sum = 0.f;
#pragma unroll
        for (int j = j0; j < j0 + 32; j++) {
            sum += proj[j * 68 + lane];
            const bool flush = (j == j0 + 31) || (src_s[j + 1] != src_s[j]);
            if (flush) {
                atomicAdd(out + (size_t)src_s[j] * 64 + lane, sum);
                sum = 0.f;
            }
        }
    }
}

extern "C" void kernel_launch(void* const* d_in, const int* in_sizes, int n_in,
                              void* d_out, int out_size, void* d_ws, size_t ws_size,
                              hipStream_t stream) {
    const float* x     = (const float*)d_in[0];
    const float* W     = (const float*)d_in[1];
    const float* b     = (const float*)d_in[2];
    const float* ea    = (const float*)d_in[3];
    const int*   edges = (const int*)d_in[4];
    float* out = (float*)d_out;

    char* ws = (char*)d_ws;
    unsigned short* xbf  = (unsigned short*)(ws + OFF_XBF);
    unsigned short* wT   = (unsigned short*)(ws + OFF_WT);
    unsigned* cnt_tot    = (unsigned*)(ws + OFF_CTOT);
    float* wgt           = (float*)(ws + OFF_WGT);
    unsigned* pe         = (unsigned*)(ws + OFF_PE);
    unsigned* pb         = (unsigned*)(ws + OFF_PB);
    int* sdst            = (int*)(ws + OFF_DST);
    int* seg             = (int*)(ws + OFF_SEG);

    // 1: out-zero, x->bf16, W^T, softmax + FUSED partition counts
    k_init<<<(NN * DD) / 256, 256, 0, stream>>>(x, W, ea, edges, xbf, wT, wgt, out, pb);

    // 2: scan of 25,600 partition counters
    k_pscan<<<1, 1024, 0, stream>>>(pb);

    // 3: partition scatter into node-buckets
    k_pscat<<<dim3(PSPLIT, TT), 256, 0, stream>>>(edges, pb, pe);

    // 4: fused node-major bucket sort (cnt_tot + seg + sdst)
    k_bsort<<<CH, 512, 0, stream>>>(pe, pb, cnt_tot, sdst, seg);

    // 5: MFMA gather-GEMM (5-pass masked) + node-keyed segmented scatter
    k_edge7<<<NETOT / 128, 256, 0, stream>>>(xbf, wT, b, sdst, seg, cnt_tot, wgt, out);
}

// Round 11
// 311.482 us; speedup vs baseline: 2.3876x; 2.3876x over previous
//
#include <hip/hip_runtime.h>
#include <hip/hip_bf16.h>

#define NN 100000
#define DD 64
#define EE 400000
#define TT 5

#define CH 160                   /* src buckets per t */
#define BPC 625                  /* NN/CH exact */
#define PSPLIT 100               /* slices per t (PESL%4==0) */
#define PESL (EE / PSPLIT)       /* 4,000 edges per slice */
#define NSB (PSPLIT * TT)        /* 500 fused pcount jobs */
#define PBN (TT * CH * PSPLIT)   /* 80,000 partition counters */
#define PB_IDX(t, c, s) ((((t) * CH + (c)) * PSPLIT) + (s))
#define PSA_B 80                 /* pscanA blocks: 80*1024 >= 80,000 */
#define NETOT (TT * EE)          /* 2,000,000 */

typedef __bf16 bf16x8 __attribute__((ext_vector_type(8)));
typedef float  f32x4  __attribute__((ext_vector_type(4)));

// ws layout (bytes) — total 40,914,240 envelope
#define OFF_XBF  0u            // N*D ushort      = 12,800,000
#define OFF_WT   12800000u     // T*64*128 ushort = 81,920
#define OFF_CTOT 12881920u     // T*N u32 (cnt_tot) = 2,000,000
#define OFF_WGT  14881920u     // T f32 (pad 128)
#define OFF_PB   14882048u     // 80,000 u32 partition counts (320,000 B)
#define OFF_BS   15202304u     // 80 u32 pscan block sums (pad 320 B)
#define OFF_PE   16886080u     // 2M u32 packed (srcl:10|dst:17) = 8,000,000
#define OFF_DST  24914240u     // 2M int (sorted dst) = 8,000,000
#define OFF_SEG  32914240u     // 2M int (seg src)    = 8,000,000 -> 40,914,240

__device__ __forceinline__ unsigned short f2bf(float f) {
    union { float f; unsigned u; } v; v.f = f;
    unsigned u = v.u;
    return (unsigned short)((u + 0x7FFFu + ((u >> 16) & 1u)) >> 16);  // RNE
}

// ---------------- Phase 1: init / convert / out-zero, FUSED pcount (500
// slice-jobs on blocks 0..499 of the 25,000-block grid) -----------------------
__global__ __launch_bounds__(256) void k_init(
        const float* __restrict__ x, const float* __restrict__ W,
        const float* __restrict__ ea, const int* __restrict__ edges,
        unsigned short* __restrict__ xbf, unsigned short* __restrict__ wT,
        float* __restrict__ wgt, float* __restrict__ out,
        unsigned* __restrict__ pcnt) {
    int i = blockIdx.x * blockDim.x + threadIdx.x;   // grid covers N*D exactly
    if (i < NN * DD) {
        out[i] = 0.0f;
        xbf[i] = f2bf(x[i]);
    }
    if (i < TT * 128 * 64) {
        int t = i >> 13;          // /8192
        int rem = i & 8191;
        int d = rem >> 7;         // /128
        int k = rem & 127;
        wT[i] = f2bf(W[t * 8192 + k * 64 + d]);   // wT[t][d][k] = W[t][k][d]
    }
    if (i == 0) {
        float m = -1e30f;
        for (int t = 0; t < TT; t++) m = fmaxf(m, ea[t]);
        float e[TT]; float s = 0.0f;
        for (int t = 0; t < TT; t++) { e[t] = __expf(ea[t] - m); s += e[t]; }
        for (int t = 0; t < TT; t++) wgt[t] = e[t] / s;
    }
    // fused pcount (block-uniform branch)
    if (blockIdx.x < NSB) {
        const int sb = blockIdx.x;
        const int t = sb / PSPLIT;
        const int s = sb - t * PSPLIT;
        __shared__ unsigned h[CH];
        if (threadIdx.x < CH) h[threadIdx.x] = 0u;
        __syncthreads();
        const int4* srcp = reinterpret_cast<const int4*>(edges + (size_t)t * 2 * EE + s * PESL);
        for (int j = threadIdx.x; j < PESL / 4; j += 256) {
            int4 v = srcp[j];
            atomicAdd(&h[(unsigned)v.x / BPC], 1u);
            atomicAdd(&h[(unsigned)v.y / BPC], 1u);
            atomicAdd(&h[(unsigned)v.z / BPC], 1u);
            atomicAdd(&h[(unsigned)v.w / BPC], 1u);
        }
        __syncthreads();
        if (threadIdx.x < CH) pcnt[PB_IDX(t, threadIdx.x, s)] = h[threadIdx.x];
    }
}

// ---------------- Phase 2a: block-local exclusive scan of pb (80 blocks),
// block totals -> bsums. Consumers add bsums[idx>>10] (add-back fused). ------
__global__ void k_pscanA(unsigned* __restrict__ pb, unsigned* __restrict__ bsums) {
    __shared__ unsigned s[1024];
    const int tid = threadIdx.x;
    const int g = blockIdx.x * 1024 + tid;
    const unsigned v = (g < PBN) ? pb[g] : 0u;
    s[tid] = v;
    __syncthreads();
    unsigned inc = v;
    for (int d = 1; d < 1024; d <<= 1) {
        unsigned a = (tid >= d) ? s[tid - d] : 0u;
        __syncthreads();
        inc += a;
        s[tid] = inc;
        __syncthreads();
    }
    if (g < PBN) pb[g] = inc - v;                 // block-local exclusive
    if (tid == 1023) bsums[blockIdx.x] = inc;     // block total
}

// ---------------- Phase 2b: exclusive scan of the 80 block sums --------------
__global__ void k_pscanB(unsigned* __restrict__ bsums) {
    __shared__ unsigned s[PSA_B];
    const int tid = threadIdx.x;                  // 128 threads
    const unsigned v = (tid < PSA_B) ? bsums[tid] : 0u;
    if (tid < PSA_B) s[tid] = v;
    __syncthreads();
    unsigned inc = v;
    for (int d = 1; d < PSA_B; d <<= 1) {
        unsigned a = (tid >= d && tid < PSA_B) ? s[tid - d] : 0u;
        __syncthreads();
        inc += a;
        if (tid < PSA_B) s[tid] = inc;
        __syncthreads();
    }
    if (tid < PSA_B) bsums[tid] = inc - v;
}

// ---------------- Phase 3: partition scatter (500 blocks).
// pe = (srcl:10 | dst:17). ----------------------------------------------------
__global__ __launch_bounds__(256) void k_pscat(const int* __restrict__ edges,
                                               const unsigned* __restrict__ pb,
                                               const unsigned* __restrict__ bsums,
                                               unsigned* __restrict__ pe) {
    const int s = blockIdx.x, t = blockIdx.y;
    __shared__ unsigned lofs[CH];
    if (threadIdx.x < CH) {
        const int idx = PB_IDX(t, threadIdx.x, s);
        lofs[threadIdx.x] = pb[idx] + bsums[idx >> 10];
    }
    __syncthreads();
    const int* srcp = edges + (size_t)t * 2 * EE + s * PESL;
    const int* dstp = srcp + EE;
    for (int i = threadIdx.x; i < PESL / 4; i += 256) {
        int4 v = reinterpret_cast<const int4*>(srcp)[i];
        int4 w = reinterpret_cast<const int4*>(dstp)[i];
        {
            unsigned c = (unsigned)v.x / BPC;
            unsigned o = atomicAdd(&lofs[c], 1u);
            pe[o] = (((unsigned)v.x - c * BPC) << 17) | (unsigned)w.x;
        }
        {
            unsigned c = (unsigned)v.y / BPC;
            unsigned o = atomicAdd(&lofs[c], 1u);
            pe[o] = (((unsigned)v.y - c * BPC) << 17) | (unsigned)w.y;
        }
        {
            unsigned c = (unsigned)v.z / BPC;
            unsigned o = atomicAdd(&lofs[c], 1u);
            pe[o] = (((unsigned)v.z - c * BPC) << 17) | (unsigned)w.z;
        }
        {
            unsigned c = (unsigned)v.w / BPC;
            unsigned o = atomicAdd(&lofs[c], 1u);
            pe[o] = (((unsigned)v.w - c * BPC) << 17) | (unsigned)w.w;
        }
    }
}

// ---------------- Phase 4: fused bucket sort (800 blocks, 6 KB LDS) ---------
__global__ __launch_bounds__(256) void k_bsort(const unsigned* __restrict__ pe,
                                               const unsigned* __restrict__ pb,
                                               const unsigned* __restrict__ bsums,
                                               unsigned* __restrict__ cnt_tot,
                                               int* __restrict__ sdst,
                                               int* __restrict__ seg) {
    const int c = blockIdx.x, t = blockIdx.y;
    const int tid = threadIdx.x;
    __shared__ unsigned h[BPC];        // 2.5 KB
    __shared__ unsigned curl[BPC];     // 2.5 KB
    __shared__ unsigned ssum[256];

    const int K = (t * CH + c) * PSPLIT;
    const unsigned st = pb[K] + bsums[K >> 10];
    const int K2 = K + PSPLIT;
    const unsigned en = (K2 >= PBN) ? (unsigned)NETOT : (pb[K2] + bsums[K2 >> 10]);

    for (int i = tid; i < BPC; i += 256) h[i] = 0u;
    __syncthreads();

    // count bins
    for (unsigned i = st + tid; i < en; i += 256)
        atomicAdd(&h[pe[i] >> 17], 1u);
    __syncthreads();

    // cnt_tot for k_edge's scale
    unsigned* outp = cnt_tot + t * NN + c * BPC;
    for (int i = tid; i < BPC; i += 256) outp[i] = h[i];

    // block-wide exclusive scan of h -> absolute curl, fused seg-run fill
    {
        const int base = tid * 3;          // 256*3 = 768 >= 625
        unsigned v[3]; unsigned sum = 0u;
#pragma unroll
        for (int j = 0; j < 3; j++) {
            int g = base + j;
            v[j] = (g < BPC) ? h[g] : 0u;
            sum += v[j];
        }
        ssum[tid] = sum;
        __syncthreads();
        unsigned inc = sum;
        for (int d = 1; d < 256; d <<= 1) {
            unsigned a = (tid >= d) ? ssum[tid - d] : 0u;
            __syncthreads();
            inc += a;
            ssum[tid] = inc;
            __syncthreads();
        }
        unsigned run = st + inc - sum;     // absolute exclusive prefix
#pragma unroll
        for (int j = 0; j < 3; j++) {
            int g = base + j;
            if (g < BPC) {
                curl[g] = run;
                const int node = c * BPC + g;
                for (unsigned jj = 0; jj < v[j]; jj++) seg[run + jj] = node;
                run += v[j];
            }
        }
    }
    __syncthreads();

    // counting-sort scatter of dst
    for (unsigned i = st + tid; i < en; i += 256) {
        unsigned p = pe[i];
        sdst[atomicAdd(&curl[p >> 17], 1u)] = (int)(p & 0x1FFFFu);
    }
}

// ---------------- Phase 5: gather -> MFMA -> wave-cooperative segmented scatter.
// EXACT R0 kernel — 184-186 us across five reproductions. CLOSED: exclusive
// ownership (R1: 386, R5: 340), global-atomic fill (R3), 2x occupancy (R6:
// 282), software pipeline (R8: 241), node-major 5-pass (R10: 628) all lost.
// 267 MB scattered fabric traffic at 1.45 TB/s — best service rate observed.
// DO NOT TOUCH. ---------------------------------------------------------------
__global__ __launch_bounds__(256) void k_edge(
    const unsigned short* __restrict__ xbf, const unsigned short* __restrict__ wT,
    const float* __restrict__ b, const int* __restrict__ sdst,
    const int* __restrict__ seg, const unsigned* __restrict__ cnt,
    const float* __restrict__ wgt, float* __restrict__ out) {
    const int t  = blockIdx.y;
    const int e0 = blockIdx.x * 128;

    __shared__ __align__(16) unsigned short Ab[128][136];   // feats tile; reused as f32 proj[128][68]
    __shared__ float scale_s[128];
    __shared__ int   src_s[132];                             // padded

    const int tid = threadIdx.x;

    // stage A: gather x rows (bf16, 128B each); thread pair per sorted edge
    {
        int e = tid >> 1, half = tid & 1;
        size_t pos = (size_t)t * EE + e0 + e;
        int idx = half ? sdst[pos] : seg[pos];
        const float4* g = reinterpret_cast<const float4*>(xbf + (size_t)idx * 64);
        float4* l = reinterpret_cast<float4*>(&Ab[e][half * 64]);
#pragma unroll
        for (int c = 0; c < 8; c++) l[c] = g[c];
        if (half == 0) {
            src_s[e] = idx;
            scale_s[e] = wgt[t] / (float)cnt[t * NN + idx];   // cnt_tot table is L2-hot
        }
    }
    __syncthreads();

    const int wv = tid >> 6, lane = tid & 63;
    const int m16 = lane & 15, quad = lane >> 4;
    const unsigned short* wrow = wT + (size_t)t * 8192;      // [d][k], 64x128

    f32x4 acc[2][4];
#pragma unroll
    for (int tm = 0; tm < 2; tm++)
#pragma unroll
        for (int tn = 0; tn < 4; tn++)
            acc[tm][tn] = (f32x4){0.f, 0.f, 0.f, 0.f};

#pragma unroll
    for (int kk = 0; kk < 128; kk += 32) {
        const int kb = kk + quad * 8;
        bf16x8 af[2], bfr[4];
#pragma unroll
        for (int tm = 0; tm < 2; tm++)
            af[tm] = *reinterpret_cast<const bf16x8*>(&Ab[wv * 32 + tm * 16 + m16][kb]);
#pragma unroll
        for (int tn = 0; tn < 4; tn++)
            bfr[tn] = *reinterpret_cast<const bf16x8*>(wrow + (tn * 16 + m16) * 128 + kb);
#pragma unroll
        for (int tm = 0; tm < 2; tm++)
#pragma unroll
            for (int tn = 0; tn < 4; tn++)
                acc[tm][tn] = __builtin_amdgcn_mfma_f32_16x16x32_bf16(
                    af[tm], bfr[tn], acc[tm][tn], 0, 0, 0);
    }

    // all waves done reading Ab before we overwrite it with f32 proj
    __syncthreads();

    float bias[4];
#pragma unroll
    for (int tn = 0; tn < 4; tn++) bias[tn] = b[t * 64 + tn * 16 + m16];

    float* proj = reinterpret_cast<float*>(&Ab[0][0]);   // [128][68] f32, stride 68
#pragma unroll
    for (int tm = 0; tm < 2; tm++) {
#pragma unroll
        for (int r = 0; r < 4; r++) {
            const int eloc = wv * 32 + tm * 16 + quad * 4 + r;   // in [wv*32, wv*32+32)
            const float s = scale_s[eloc];
#pragma unroll
            for (int tn = 0; tn < 4; tn++) {
                float v = acc[tm][tn][r] + bias[tn];
                v = v > 0.f ? v : 0.f;
                proj[eloc * 68 + tn * 16 + m16] = v * s;
            }
        }
    }
    // NO barrier: wave wv wrote exactly proj rows [wv*32, wv*32+32) and reads
    // only those below. (src_s/scale_s were synced by the earlier barrier.)

    // wave-cooperative segmented reduce: lane = feature, walk 32 sorted edges,
    // flush one COALESCED 256B atomic burst per segment.
    {
        const int j0 = wv * 32;
        float sum = 0.f;
#pragma unroll
        for (int j = j0; j < j0 + 32; j++) {
            sum += proj[j * 68 + lane];
            const bool flush = (j == j0 + 31) || (src_s[j + 1] != src_s[j]);
            if (flush) {
                atomicAdd(out + (size_t)src_s[j] * 64 + lane, sum);
                sum = 0.f;
            }
        }
    }
}

extern "C" void kernel_launch(void* const* d_in, const int* in_sizes, int n_in,
                              void* d_out, int out_size, void* d_ws, size_t ws_size,
                              hipStream_t stream) {
    const float* x     = (const float*)d_in[0];
    const float* W     = (const float*)d_in[1];
    const float* b     = (const float*)d_in[2];
    const float* ea    = (const float*)d_in[3];
    const int*   edges = (const int*)d_in[4];
    float* out = (float*)d_out;

    char* ws = (char*)d_ws;
    unsigned short* xbf  = (unsigned short*)(ws + OFF_XBF);
    unsigned short* wT   = (unsigned short*)(ws + OFF_WT);
    unsigned* cnt_tot    = (unsigned*)(ws + OFF_CTOT);
    float* wgt           = (float*)(ws + OFF_WGT);
    unsigned* pb         = (unsigned*)(ws + OFF_PB);
    unsigned* bsums      = (unsigned*)(ws + OFF_BS);
    unsigned* pe         = (unsigned*)(ws + OFF_PE);
    int* sdst            = (int*)(ws + OFF_DST);
    int* seg             = (int*)(ws + OFF_SEG);

    // 1: out-zero, x->bf16, W^T, softmax + FUSED partition counts
    k_init<<<(NN * DD) / 256, 256, 0, stream>>>(x, W, ea, edges, xbf, wT, wgt, out, pb);

    // 2: two-level scan of 80,000 partition counters (add-back fused downstream)
    k_pscanA<<<PSA_B, 1024, 0, stream>>>(pb, bsums);
    k_pscanB<<<1, 128, 0, stream>>>(bsums);

    // 3: partition scatter (500 blocks)
    k_pscat<<<dim3(PSPLIT, TT), 256, 0, stream>>>(edges, pb, bsums, pe);

    // 4: fused bucket sort (800 blocks)
    k_bsort<<<dim3(CH, TT), 256, 0, stream>>>(pe, pb, bsums, cnt_tot, sdst, seg);

    // 5: MFMA gather-GEMM + wave-cooperative segmented scatter (R0 proven)
    dim3 grid(EE / 128, TT);
    k_edge<<<grid, 256, 0, stream>>>(xbf, wT, b, sdst, seg, cnt_tot, wgt, out);
}